// Round 6
// baseline (499.492 us; speedup 1.0000x reference)
//
#include <hip/hip_runtime.h>
#include <hip/hip_bf16.h>
#include <hip/hip_fp16.h>

// ============================================================================
// MinGRUCell forward, MI355X (gfx950).  Round 11 = round 8/10 + pipelined GEMM.
//
// Round-10 instrumentation resolved the accounting: harness re-poison fills
// (512 MiB @ 77us each) are a fixed ~154us inside dur_us; our kernels are
// near their BW floors EXCEPT the GEMM (188us @ ~880 TF vs 1563 TF proven
// for the 8-phase schedule).  This round: 4-phase-per-K-tile pipelined GEMM,
// derived to avoid round-7's failure (burst staging, no interleave):
//   - BM=128 BN=256 BK=64, 512 thr / 8 waves, per-wave 64x64 acc[4][4]
//   - frags ds_read one FULL K-tile ahead (tile t read during t-1's P2/P3)
//     so tile t's buffer is read-free during its own phases -> tile t+2's
//     staging spreads 2/2/1/1 dma16 across P0-P3 with zero read/DMA overlap
//   - vmcnt(5) once per tile (counted, never 0 until the tail)
//   - one lgkmcnt(0) per tile (before final barrier) for cross-wave safety
//   - setprio(1) around each 8-MFMA quadrant cluster
// Fused gate/phase1 epilogue unchanged (per-wave 64x64 identical to round 8).
//
// Workspace: wb bf16 4MiB | avbuf half2 128MiB | seed 4MiB | biasp 8KB
// d_out scratch (until phase3 overwrites): xb [0,64Mi) | Aar,Bar [64,72Mi)
// ============================================================================

#define N_B   8
#define L_SEQ 4096
#define H_DIM 1024
#define K_DIM 1024
#define O_DIM 2048
#define M_TOT (N_B * L_SEQ)      // 32768 GEMM rows

#define BM 128
#define BN 256
#define BK 64
#define KTILES (K_DIM / BK)      // 16

#define NCHUNK 128
#define CLEN   (L_SEQ / NCHUNK)  // 32
#define NCH    (N_B * H_DIM)     // 8192 channels

typedef unsigned short ushort_t;
typedef unsigned short us8 __attribute__((ext_vector_type(8)));
typedef __bf16 v8bf __attribute__((ext_vector_type(8)));
typedef float f32x4 __attribute__((ext_vector_type(4)));

static __device__ __forceinline__ ushort_t f2bf(float f) {
    __hip_bfloat16 h = __float2bfloat16(f);   // RTN
    return *reinterpret_cast<ushort_t*>(&h);
}

// async global->LDS DMA, 16B per lane, LDS dest = wave-uniform base + lane*16
static __device__ __forceinline__ void dma16(const ushort_t* g, ushort_t* l) {
    __builtin_amdgcn_global_load_lds(
        (const __attribute__((address_space(1))) unsigned int*)g,
        (__attribute__((address_space(3))) unsigned int*)l,
        16, 0, 0);
}

// ---------------------------------------------------------------------------
// fp32 -> bf16 (8 elems/thread), straight copy (used for X)
// ---------------------------------------------------------------------------
__global__ __launch_bounds__(256) void cvt_f32_bf16(
    const float* __restrict__ src, ushort_t* __restrict__ dst)
{
    const int i = blockIdx.x * 256 + threadIdx.x;
    const float4 f0 = ((const float4*)src)[2 * i];
    const float4 f1 = ((const float4*)src)[2 * i + 1];
    us8 o;
    o[0] = f2bf(f0.x); o[1] = f2bf(f0.y); o[2] = f2bf(f0.z); o[3] = f2bf(f0.w);
    o[4] = f2bf(f1.x); o[5] = f2bf(f1.y); o[6] = f2bf(f1.z); o[7] = f2bf(f1.w);
    ((us8*)dst)[i] = o;
}

// ---------------------------------------------------------------------------
// fp32 -> bf16 W with row permutation + bias permutation (merged).
// dest row o' in 16-row blocks B=o'>>4, t=o'&15:
//   B even -> z row (B>>1)*16+t ; B odd -> h row 1024+(B>>1)*16+t.
// ---------------------------------------------------------------------------
__global__ __launch_bounds__(256) void cvt_w_perm(
    const float* __restrict__ src, ushort_t* __restrict__ dst,
    const float* __restrict__ b, float* __restrict__ bp)
{
    const int i  = blockIdx.x * 256 + threadIdx.x;  // 262144 threads
    const int op = i >> 7;                          // dest row 0..2047
    const int k  = (i & 127) * 8;
    const int B  = op >> 4, t = op & 15;
    const int orig = (B & 1) * 1024 + (B >> 1) * 16 + t;
    const float4* s = (const float4*)(src + (size_t)orig * K_DIM + k);
    const float4 f0 = s[0], f1 = s[1];
    us8 o;
    o[0] = f2bf(f0.x); o[1] = f2bf(f0.y); o[2] = f2bf(f0.z); o[3] = f2bf(f0.w);
    o[4] = f2bf(f1.x); o[5] = f2bf(f1.y); o[6] = f2bf(f1.z); o[7] = f2bf(f1.w);
    *(us8*)(dst + (size_t)op * K_DIM + k) = o;

    if (i < O_DIM) {                                // fused bias permutation
        const int Bb = i >> 4, tb = i & 15;
        bp[i] = b[(Bb & 1) * 1024 + (Bb >> 1) * 16 + tb];
    }
}

// ---------------------------------------------------------------------------
// Gating math.  a = sigmoid(-z), v = sigmoid(z)*g(hi)
// g(x) = x+0.5 (x>=0) else sigmoid(x)
// ---------------------------------------------------------------------------
__device__ __forceinline__ void gate_av(float z, float hi, float& a, float& v)
{
    const float e  = __expf(-z);
    const float sz = 1.0f / (1.0f + e);        // sigmoid(z)
    a = e * sz;                                // sigmoid(-z)
    const float g = (hi >= 0.0f) ? (hi + 0.5f)
                                 : (1.0f / (1.0f + __expf(-hi)));
    v = sz * g;
}

// ---------------------------------------------------------------------------
// Pipelined GEMM + fused gate/phase1 epilogue.
// ---------------------------------------------------------------------------

// stage one 64-row round r of K-tile kt into buffer b (2 per A-tile, 4 per B)
#define STG_A(b, kt, r) dma16(gA + (size_t)(r) * 64 * K_DIM + (size_t)(kt) * BK, \
                              &As[b][((r) * 64 + wave * 8) * BK])
#define STG_B(b, kt, r) dma16(gB + (size_t)(r) * 64 * K_DIM + (size_t)(kt) * BK, \
                              &Bs[b][((r) * 64 + wave * 8) * BK])

// read half h (frag rows 2h,2h+1) of the NEXT tile's A and B frags from buf rb
#define RD_HALF(NA, NB, rb, h)                                                \
    _Pragma("unroll") for (int i2_ = 0; i2_ < 2; ++i2_)                       \
    _Pragma("unroll") for (int s_ = 0; s_ < 2; ++s_) {                        \
        NA[(h) * 2 + i2_][s_] = *(const v8bf*)&As[rb][offA[(h) * 2 + i2_][s_]]; \
        NB[(h) * 2 + i2_][s_] = *(const v8bf*)&Bs[rb][offB[(h) * 2 + i2_][s_]]; \
    }

// 8 MFMAs of quadrant p (ih=p>>1 rows, jh=p&1 cols) from current frag set
#define QUAD(p, CA, CB) {                                                     \
    const int ih_ = (p) >> 1, jh_ = (p) & 1;                                  \
    _Pragma("unroll") for (int i2_ = 0; i2_ < 2; ++i2_)                       \
    _Pragma("unroll") for (int j2_ = 0; j2_ < 2; ++j2_)                       \
    _Pragma("unroll") for (int s_ = 0; s_ < 2; ++s_)                          \
        acc[ih_ * 2 + i2_][jh_ * 2 + j2_] =                                   \
            __builtin_amdgcn_mfma_f32_16x16x32_bf16(                          \
                CA[ih_ * 2 + i2_][s_], CB[jh_ * 2 + j2_][s_],                 \
                acc[ih_ * 2 + i2_][jh_ * 2 + j2_], 0, 0, 0); }

#define BAR() __builtin_amdgcn_s_barrier()
#define PRIO(x) __builtin_amdgcn_s_setprio(x)

// one K-tile t: compute from (CA,CB); read tile t+1 into (NA,NB) at P2/P3;
// stage tile t+2 into buf cb at P0..P3 (2/2/1/1 loads).
#define TILE(t, cb, CA, CB, NA, NB, sg, rd)                                   \
    {                                                                         \
        /* P0 */                                                              \
        if (sg) { STG_A(cb, (t) + 2, 0); STG_A(cb, (t) + 2, 1); }             \
        BAR();                                                                \
        PRIO(1); QUAD(0, CA, CB); PRIO(0);                                    \
        BAR();                                                                \
        /* P1 */                                                              \
        if (sg) { STG_B(cb, (t) + 2, 0); STG_B(cb, (t) + 2, 1); }             \
        BAR();                                                                \
        PRIO(1); QUAD(1, CA, CB); PRIO(0);                                    \
        BAR();                                                                \
        /* P2 */                                                              \
        if (sg) { STG_B(cb, (t) + 2, 2); }                                    \
        if (rd) {                                                             \
            if (sg) { asm volatile("s_waitcnt vmcnt(5)" ::: "memory"); }      \
            else    { asm volatile("s_waitcnt vmcnt(0)" ::: "memory"); }      \
            RD_HALF(NA, NB, (cb) ^ 1, 0);                                     \
        }                                                                     \
        BAR();                                                                \
        PRIO(1); QUAD(2, CA, CB); PRIO(0);                                    \
        BAR();                                                                \
        /* P3 */                                                              \
        if (sg) { STG_B(cb, (t) + 2, 3); }                                    \
        if (rd) { RD_HALF(NA, NB, (cb) ^ 1, 1); }                             \
        asm volatile("s_waitcnt lgkmcnt(0)" ::: "memory");                    \
        __builtin_amdgcn_sched_barrier(0);                                    \
        PRIO(1); QUAD(3, CA, CB); PRIO(0);                                    \
        BAR();                                                                \
    }

__global__ __launch_bounds__(512, 2) void gemm_zh(
    const ushort_t* __restrict__ Xb,       // (M_TOT, K) bf16 bits
    const ushort_t* __restrict__ Wb,       // (O_DIM, K) bf16 bits, PERMUTED
    const float* __restrict__ biasp,       // (O_DIM) fp32, PERMUTED
    __half2* __restrict__ avbuf,           // (M_TOT, H_DIM) half2 {a,v}
    float* __restrict__ Aar,               // (NCHUNK, NCH) chunk A
    float* __restrict__ Bar)               // (NCHUNK, NCH) chunk B
{
    __shared__ ushort_t As[2][BM * BK];    // 2 x 16 KiB
    __shared__ ushort_t Bs[2][BN * BK];    // 2 x 32 KiB   (96 KiB total)

    const int tid    = threadIdx.x;
    const int wave   = tid >> 6;           // 0..7
    const int lane   = tid & 63;
    const int lane15 = lane & 15;
    const int quad   = lane >> 4;
    const int wm     = (wave >> 2) * 64;   // 0,64      (M direction)
    const int wn     = (wave & 3) * 64;    // 0..192    (N direction)

    const int n0 = blockIdx.x * BN;        // n fast -> A-panel L2 reuse
    const int m0 = blockIdx.y * BM;

    // staging source (xor-swizzled chunk within row; linear LDS dest)
    const int lrow = lane >> 3;            // 0..7
    const int jj   = (lane & 7) ^ lrow;
    const ushort_t* gA = Xb + (size_t)(m0 + wave * 8 + lrow) * K_DIM + jj * 8;
    const ushort_t* gB = Wb + (size_t)(n0 + wave * 8 + lrow) * K_DIM + jj * 8;

    // fragment read offsets (xor matches staging swizzle)
    int offA[4][2], offB[4][2];
#pragma unroll
    for (int i = 0; i < 4; ++i)
#pragma unroll
        for (int s = 0; s < 2; ++s) {
            const int rA = wm + i * 16 + lane15;
            offA[i][s] = rA * BK + (((s * 4 + quad) ^ (rA & 7)) * 8);
            const int rB = wn + i * 16 + lane15;
            offB[i][s] = rB * BK + (((s * 4 + quad) ^ (rB & 7)) * 8);
        }

    const f32x4 fzero = {0.f, 0.f, 0.f, 0.f};
    f32x4 acc[4][4];
#pragma unroll
    for (int i = 0; i < 4; ++i)
#pragma unroll
        for (int j = 0; j < 4; ++j)
            acc[i][j] = fzero;

    v8bf a0[4][2], b0[4][2], a1[4][2], b1[4][2];

    // ---- prologue: stage tiles 0,1; read tile 0 frags ---------------------
#pragma unroll
    for (int r = 0; r < 2; ++r) STG_A(0, 0, r);
#pragma unroll
    for (int r = 0; r < 4; ++r) STG_B(0, 0, r);
#pragma unroll
    for (int r = 0; r < 2; ++r) STG_A(1, 1, r);
#pragma unroll
    for (int r = 0; r < 4; ++r) STG_B(1, 1, r);
    asm volatile("s_waitcnt vmcnt(6)" ::: "memory");   // tile 0 landed
    BAR();
    RD_HALF(a0, b0, 0, 0);
    RD_HALF(a0, b0, 0, 1);
    asm volatile("s_waitcnt lgkmcnt(0)" ::: "memory"); // drain before staging buf0
    BAR();

    // ---- main loop: 2 K-tiles per iteration -------------------------------
#pragma unroll 1
    for (int tt = 0; tt < KTILES / 2; ++tt) {
        const int  t0 = 2 * tt, t1 = 2 * tt + 1;
        const bool sg = (tt < KTILES / 2 - 1);
        TILE(t0, 0, a0, b0, a1, b1, sg, true);
        TILE(t1, 1, a1, b1, a0, b0, sg, sg);
    }

    // ---- fused epilogue (identical math to round 8) -----------------------
    // columns: j even = z-block, j odd = h-block of same 16 channels.
    float bv[4];
#pragma unroll
    for (int j = 0; j < 4; ++j)
        bv[j] = biasp[n0 + wn + j * 16 + lane15];

    const int chbase = ((n0 + wn) >> 1) + lane15;   // + jp*16

    float Ai[4][2], Bi[4][2];   // per-(i-frag, jp) 16-row affine summaries

#pragma unroll
    for (int i = 0; i < 4; ++i) {
        float A[2] = {1.f, 1.f};
        float Bc[2] = {0.f, 0.f};
#pragma unroll
        for (int r = 0; r < 4; ++r) {
            const size_t row = (size_t)(m0 + wm + i * 16 + quad * 4 + r);
            __half2* prow = avbuf + row * H_DIM + chbase;
#pragma unroll
            for (int jp = 0; jp < 2; ++jp) {
                const float z  = acc[i][2 * jp][r]     + bv[2 * jp];
                const float hh = acc[i][2 * jp + 1][r] + bv[2 * jp + 1];
                float a, v;
                gate_av(z, hh, a, v);
                const __half2 h2 = __floats2half2_rn(a, v);
                prow[jp * 16] = h2;
                // compose with the SAME fp16-rounded values phase3 will use
                const float2 f = __half22float2(h2);
                Bc[jp] = fmaf(f.x, Bc[jp], f.y);
                A[jp] *= f.x;
            }
        }
        // ordered compose across quads (rows i*16 + quad*4 + r are
        // (quad,r)-lexicographic): butterfly on lane bits 16 and 32.
#pragma unroll
        for (int jp = 0; jp < 2; ++jp) {
#pragma unroll
            for (int d = 16; d < 64; d <<= 1) {
                const float Ay = __shfl_xor(A[jp],  d);
                const float By = __shfl_xor(Bc[jp], d);
                // bit set -> I am the LATER block: (A,B) o (Ay,By)
                Bc[jp] = (lane & d) ? fmaf(A[jp], By, Bc[jp])
                                    : fmaf(Ay, Bc[jp], By);
                A[jp] *= Ay;
            }
            Ai[i][jp] = A[jp];
            Bi[i][jp] = Bc[jp];
        }
    }

    // chunk (32 rows) = frags {2cc, 2cc+1}; all quads hold identical values,
    // quad 0 writes.
    if (lane < 16) {
#pragma unroll
        for (int cc = 0; cc < 2; ++cc) {
            const int grow = m0 + wm + cc * 32;
            const int n    = grow >> 12;                  // batch
            const int cch  = (grow & (L_SEQ - 1)) >> 5;   // chunk id
            const size_t o = (size_t)cch * NCH + (size_t)n * H_DIM + chbase;
#pragma unroll
            for (int jp = 0; jp < 2; ++jp) {
                const float A0 = Ai[2 * cc][jp],     B0 = Bi[2 * cc][jp];
                const float A1 = Ai[2 * cc + 1][jp], B1 = Bi[2 * cc + 1][jp];
                Aar[o + jp * 16] = A1 * A0;
                Bar[o + jp * 16] = fmaf(A1, B0, B1);
            }
        }
    }
}

// ---------------------------------------------------------------------------
// Phase 2: compose NCHUNK chunk summaries per channel, seeded with hx (fp32).
// ---------------------------------------------------------------------------
__global__ __launch_bounds__(256) void scan_phase2(
    const float* __restrict__ Aar, const float* __restrict__ Bar,
    const float* __restrict__ hx, float* __restrict__ seed)
{
    const int ch = blockIdx.x * 256 + threadIdx.x;    // 0..8191
    float carry = hx[ch];
#pragma unroll 8
    for (int c = 0; c < NCHUNK; ++c) {
        seed[c * NCH + ch] = carry;
        carry = fmaf(Aar[c * NCH + ch], carry, Bar[c * NCH + ch]);
    }
}

// ---------------------------------------------------------------------------
// Phase 3: pure replay from seed: h = fma(a, h, v).  4 ch/thread, 16B av
// loads, nontemporal fp32 stores.
// ---------------------------------------------------------------------------
__global__ __launch_bounds__(256) void scan_phase3(
    const __half2* __restrict__ avbuf,
    const float* __restrict__ seed, float* __restrict__ out)
{
    const int idx = blockIdx.x * 256 + threadIdx.x;
    const int h4  = (idx & 255) << 2;
    const int n   = (idx >> 8) & 7;
    const int c   = idx >> 11;
    const size_t base = ((size_t)(n * L_SEQ + c * CLEN)) * H_DIM + h4;
    const float4* avp = (const float4*)(avbuf + base);  // 4 half2 = 16B
    float* op = out + base;

    const size_t so = (size_t)c * NCH + n * H_DIM + h4;
    float h0[4];
    *(f32x4*)h0 = *(const f32x4*)(seed + so);

#pragma unroll 8
    for (int s = 0; s < CLEN; ++s) {
        float4 avr = avp[(size_t)s * (H_DIM / 4)];
        const __half2* a2 = (const __half2*)&avr;
#pragma unroll
        for (int j = 0; j < 4; ++j) {
            const float2 av = __half22float2(a2[j]);
            h0[j] = fmaf(av.x, h0[j], av.y);
        }
        f32x4 hv = *(const f32x4*)h0;
        __builtin_nontemporal_store(hv, (f32x4*)(op + (size_t)s * H_DIM));
    }
}

// ---------------------------------------------------------------------------
extern "C" void kernel_launch(void* const* d_in, const int* in_sizes, int n_in,
                              void* d_out, int out_size, void* d_ws, size_t ws_size,
                              hipStream_t stream)
{
    const float* X    = (const float*)d_in[0];   // x  (8,4096,1024) fp32
    const float* Wm   = (const float*)d_in[1];   // W  (2048,1024)   fp32
    const float* bias = (const float*)d_in[2];   // b  (2048)        fp32
    const float* hx   = (const float*)d_in[3];   // hx (8,1024)      fp32
    float* out = (float*)d_out;                  // (8,4096,1024)    fp32

    char* ws = (char*)d_ws;
    ushort_t* wb   = (ushort_t*)ws;                                 //   4 MiB
    __half2*  avbuf = (__half2*)(ws + (size_t)O_DIM * K_DIM * 2);   // 128 MiB
    float*    seed = (float*)((char*)avbuf + (size_t)M_TOT * H_DIM * 4); // 4 MiB
    float*    biasp = seed + (size_t)NCHUNK * NCH;                  //   8 KiB

    // d_out (128 MiB) doubles as scratch until phase3 overwrites it:
    //   bytes [0, 64Mi):   x_bf16  (M_TOT*K_DIM*2 B = exactly half)
    //   bytes [64Mi,72Mi): Aar, Bar (NCHUNK*NCH fp32 each)
    ushort_t* xb = (ushort_t*)d_out;
    float* Aar = out + (size_t)M_TOT * H_DIM / 2;      // true halfway point
    float* Bar = Aar + (size_t)NCHUNK * NCH;

    cvt_w_perm<<<O_DIM * K_DIM / 8 / 256, 256, 0, stream>>>(Wm, wb, bias, biasp);
    cvt_f32_bf16<<<M_TOT * K_DIM / 8 / 256, 256, 0, stream>>>(X, xb);

    dim3 ggrid(O_DIM / BN, M_TOT / BM);          // (8, 256): n fast for reuse
    gemm_zh<<<ggrid, 512, 0, stream>>>(xb, wb, biasp, avbuf, Aar, Bar);

    scan_phase2<<<NCH / 256, 256, 0, stream>>>(Aar, Bar, hx, seed);

    const int p3_blocks = (NCH / 4) * NCHUNK / 256;    // 1024
    scan_phase3<<<p3_blocks, 256, 0, stream>>>(avbuf, seed, out);
}

// Round 7
// 440.100 us; speedup vs baseline: 1.1350x; 1.1350x over previous
//
#include <hip/hip_runtime.h>
#include <hip/hip_bf16.h>
#include <hip/hip_fp16.h>

// ============================================================================
// MinGRUCell forward, MI355X (gfx950).  Round 12 = faithful m201-template GEMM.
//
// 256x256 tile, BK=64, 512 thr / 8 waves (2M x 4N), per-wave 128x64 acc[8][4].
// LDS = 4 half-slots per matrix (parity x half, 128x64 bf16 = 16KB each).
// Per phase q of tile t: {ds_read A i=2q,2q+1 (+all B at q0); stage ONE half;
//   fence; barrier; lgkmcnt(0)+sched_barrier(0); setprio(1); 16 MFMA;
//   setprio(0); barrier}.  Stages: q0/q1 = A(t+1) (opposite-parity slots),
//   q2/q3 = B(t+2) (same-parity, free since q0).  vmcnt(4) at q3 only
//   (counted: newest 4 = B(t+2) in flight; A(t+1)/B(t+1) confirmed).
//   vmcnt(0) once at t=14, none at t=15.  Race-freedom fully derived.
// Accumulation order (kt, s) identical to round 8 -> absmax must stay 0.03125.
//
// Fused gate/phase1 epilogue (round 8) generalized to 8 frags / 4 chunks.
// Scan phases unchanged.
//
// Workspace: wb bf16 4MiB | avbuf half2 128MiB | seed 4MiB | biasp 8KB
// d_out scratch (until phase3 overwrites): xb [0,64Mi) | Aar,Bar [64,72Mi)
// ============================================================================

#define N_B   8
#define L_SEQ 4096
#define H_DIM 1024
#define K_DIM 1024
#define O_DIM 2048
#define M_TOT (N_B * L_SEQ)      // 32768 GEMM rows

#define BM 256
#define BN 256
#define BK 64
#define KTILES (K_DIM / BK)      // 16

#define NCHUNK 128
#define CLEN   (L_SEQ / NCHUNK)  // 32
#define NCH    (N_B * H_DIM)     // 8192 channels

typedef unsigned short ushort_t;
typedef unsigned short us8 __attribute__((ext_vector_type(8)));
typedef __bf16 v8bf __attribute__((ext_vector_type(8)));
typedef float f32x4 __attribute__((ext_vector_type(4)));

static __device__ __forceinline__ ushort_t f2bf(float f) {
    __hip_bfloat16 h = __float2bfloat16(f);   // RTN
    return *reinterpret_cast<ushort_t*>(&h);
}

// async global->LDS DMA, 16B per lane, LDS dest = wave-uniform base + lane*16
static __device__ __forceinline__ void dma16(const ushort_t* g, ushort_t* l) {
    __builtin_amdgcn_global_load_lds(
        (const __attribute__((address_space(1))) unsigned int*)g,
        (__attribute__((address_space(3))) unsigned int*)l,
        16, 0, 0);
}

// ---------------------------------------------------------------------------
// fp32 -> bf16 (8 elems/thread), straight copy (used for X)
// ---------------------------------------------------------------------------
__global__ __launch_bounds__(256) void cvt_f32_bf16(
    const float* __restrict__ src, ushort_t* __restrict__ dst)
{
    const int i = blockIdx.x * 256 + threadIdx.x;
    const float4 f0 = ((const float4*)src)[2 * i];
    const float4 f1 = ((const float4*)src)[2 * i + 1];
    us8 o;
    o[0] = f2bf(f0.x); o[1] = f2bf(f0.y); o[2] = f2bf(f0.z); o[3] = f2bf(f0.w);
    o[4] = f2bf(f1.x); o[5] = f2bf(f1.y); o[6] = f2bf(f1.z); o[7] = f2bf(f1.w);
    ((us8*)dst)[i] = o;
}

// ---------------------------------------------------------------------------
// fp32 -> bf16 W with row permutation + bias permutation (merged).
// dest row o' in 16-row blocks B=o'>>4, t=o'&15:
//   B even -> z row (B>>1)*16+t ; B odd -> h row 1024+(B>>1)*16+t.
// ---------------------------------------------------------------------------
__global__ __launch_bounds__(256) void cvt_w_perm(
    const float* __restrict__ src, ushort_t* __restrict__ dst,
    const float* __restrict__ b, float* __restrict__ bp)
{
    const int i  = blockIdx.x * 256 + threadIdx.x;  // 262144 threads
    const int op = i >> 7;                          // dest row 0..2047
    const int k  = (i & 127) * 8;
    const int B  = op >> 4, t = op & 15;
    const int orig = (B & 1) * 1024 + (B >> 1) * 16 + t;
    const float4* s = (const float4*)(src + (size_t)orig * K_DIM + k);
    const float4 f0 = s[0], f1 = s[1];
    us8 o;
    o[0] = f2bf(f0.x); o[1] = f2bf(f0.y); o[2] = f2bf(f0.z); o[3] = f2bf(f0.w);
    o[4] = f2bf(f1.x); o[5] = f2bf(f1.y); o[6] = f2bf(f1.z); o[7] = f2bf(f1.w);
    *(us8*)(dst + (size_t)op * K_DIM + k) = o;

    if (i < O_DIM) {                                // fused bias permutation
        const int Bb = i >> 4, tb = i & 15;
        bp[i] = b[(Bb & 1) * 1024 + (Bb >> 1) * 16 + tb];
    }
}

// ---------------------------------------------------------------------------
// Gating math.  a = sigmoid(-z), v = sigmoid(z)*g(hi)
// g(x) = x+0.5 (x>=0) else sigmoid(x)
// ---------------------------------------------------------------------------
__device__ __forceinline__ void gate_av(float z, float hi, float& a, float& v)
{
    const float e  = __expf(-z);
    const float sz = 1.0f / (1.0f + e);        // sigmoid(z)
    a = e * sz;                                // sigmoid(-z)
    const float g = (hi >= 0.0f) ? (hi + 0.5f)
                                 : (1.0f / (1.0f + __expf(-hi)));
    v = sz * g;
}

// ---------------------------------------------------------------------------
// Template GEMM + fused gate/phase1 epilogue.
// ---------------------------------------------------------------------------

// stage half h of A(tile tt) into parity-P slots (2 dma16 per thread)
#define STG_A(P, tt, h) do {                                                  \
    dma16(gA + (size_t)((h) * 128)      * K_DIM + (size_t)(tt) * BK,          \
          &As[((P) * 2 + (h)) * 8192 + (wave * 8) * 64]);                     \
    dma16(gA + (size_t)((h) * 128 + 64) * K_DIM + (size_t)(tt) * BK,          \
          &As[((P) * 2 + (h)) * 8192 + (64 + wave * 8) * 64]);                \
} while (0)
#define STG_B(P, tt, h) do {                                                  \
    dma16(gB + (size_t)((h) * 128)      * K_DIM + (size_t)(tt) * BK,          \
          &Bs[((P) * 2 + (h)) * 8192 + (wave * 8) * 64]);                     \
    dma16(gB + (size_t)((h) * 128 + 64) * K_DIM + (size_t)(tt) * BK,          \
          &Bs[((P) * 2 + (h)) * 8192 + (64 + wave * 8) * 64]);                \
} while (0)

#define VM4 asm volatile("s_waitcnt vmcnt(4)" ::: "memory")
#define VM0 asm volatile("s_waitcnt vmcnt(0)" ::: "memory")

// phase iq of a tile with parity P: ds_read (+B at iq==0), stage, sync, MFMA
#define PHASE(P, iq, STGS, VMS)                                               \
    {                                                                         \
        v8bf af[2][2];                                                        \
        if ((iq) == 0) {                                                      \
            _Pragma("unroll") for (int j_ = 0; j_ < 4; ++j_)                  \
            _Pragma("unroll") for (int s_ = 0; s_ < 2; ++s_)                  \
                bfr[j_][s_] = *(const v8bf*)&Bs[bbase + (P) * 16384 +         \
                                                j_ * 1024 + aoff[s_]];        \
        }                                                                     \
        _Pragma("unroll") for (int u_ = 0; u_ < 2; ++u_)                      \
        _Pragma("unroll") for (int s_ = 0; s_ < 2; ++s_)                      \
            af[u_][s_] = *(const v8bf*)&As[abase + (P) * 16384 +              \
                                           ((iq) * 2 + u_) * 1024 + aoff[s_]];\
        STGS;                                                                 \
        VMS;                                                                  \
        asm volatile("" ::: "memory");                                        \
        __builtin_amdgcn_s_barrier();                                         \
        asm volatile("s_waitcnt lgkmcnt(0)" ::: "memory");                    \
        __builtin_amdgcn_sched_barrier(0);                                    \
        __builtin_amdgcn_s_setprio(1);                                        \
        _Pragma("unroll") for (int s_ = 0; s_ < 2; ++s_)                      \
        _Pragma("unroll") for (int u_ = 0; u_ < 2; ++u_)                      \
        _Pragma("unroll") for (int j_ = 0; j_ < 4; ++j_)                      \
            acc[(iq) * 2 + u_][j_] = __builtin_amdgcn_mfma_f32_16x16x32_bf16( \
                af[u_][s_], bfr[j_][s_], acc[(iq) * 2 + u_][j_], 0, 0, 0);    \
        __builtin_amdgcn_s_setprio(0);                                        \
        __builtin_amdgcn_s_barrier();                                         \
    }

// tile t (parity P): stage A(t+1) at q0/q1 (parity P^1), B(t+2) at q2/q3
// (parity P, slots free since this tile's q0 barrier).
#define TILE(t, P, SGA, SGB, VMS)                                             \
    PHASE(P, 0, { if (SGA) STG_A((P) ^ 1, (t) + 1, 0); }, {});                \
    PHASE(P, 1, { if (SGA) STG_A((P) ^ 1, (t) + 1, 1); }, {});                \
    PHASE(P, 2, { if (SGB) STG_B((P), (t) + 2, 0); }, {});                    \
    PHASE(P, 3, { if (SGB) STG_B((P), (t) + 2, 1); }, VMS);

__global__ __launch_bounds__(512, 2) void gemm_zh(
    const ushort_t* __restrict__ Xb,       // (M_TOT, K) bf16 bits
    const ushort_t* __restrict__ Wb,       // (O_DIM, K) bf16 bits, PERMUTED
    const float* __restrict__ biasp,       // (O_DIM) fp32, PERMUTED
    __half2* __restrict__ avbuf,           // (M_TOT, H_DIM) half2 {a,v}
    float* __restrict__ Aar,               // (NCHUNK, NCH) chunk A
    float* __restrict__ Bar)               // (NCHUNK, NCH) chunk B
{
    __shared__ ushort_t As[4 * 8192];      // 4 half-slots x 16KB = 64KB
    __shared__ ushort_t Bs[4 * 8192];      // 64KB  (128KB total)

    const int tid    = threadIdx.x;
    const int wave   = tid >> 6;           // 0..7
    const int lane   = tid & 63;
    const int lane15 = lane & 15;
    const int quad   = lane >> 4;
    const int wr     = wave >> 2;          // 0..1 (M)
    const int wc     = wave & 3;           // 0..3 (N)

    const int n0 = blockIdx.x * BN;        // 8 n-blocks
    const int m0 = blockIdx.y * BM;        // 128 m-blocks

    // staging source (xor-swizzled chunk within row; linear LDS dest)
    const int lrow = lane >> 3;            // 0..7
    const int jj   = (lane & 7) ^ lrow;
    const ushort_t* gA = Xb + (size_t)(m0 + wave * 8 + lrow) * K_DIM + jj * 8;
    const ushort_t* gB = Wb + (size_t)(n0 + wave * 8 + lrow) * K_DIM + jj * 8;

    // fragment read offsets: row-in-slot * 64 + xor-chunk
    int aoff[2];
#pragma unroll
    for (int s = 0; s < 2; ++s)
        aoff[s] = lane15 * 64 + (((s * 4 + quad) ^ (lane15 & 7)) * 8);
    const int abase = wr * 8192;                       // + P*16384
    const int bbase = (wc >> 1) * 8192 + (wc & 1) * 4096;

    const f32x4 fzero = {0.f, 0.f, 0.f, 0.f};
    f32x4 acc[8][4];
#pragma unroll
    for (int i = 0; i < 8; ++i)
#pragma unroll
        for (int j = 0; j < 4; ++j)
            acc[i][j] = fzero;

    v8bf bfr[4][2];

    // ---- prologue: stage A(0),B(0) (parity0) + B(1) (parity1) -------------
    STG_A(0, 0, 0); STG_A(0, 0, 1);
    STG_B(0, 0, 0); STG_B(0, 0, 1);
    STG_B(1, 1, 0); STG_B(1, 1, 1);
    VM4;                                   // A(0),B(0) landed; B(1) in flight
    __builtin_amdgcn_s_barrier();

    // ---- main loop: 2 tiles per iteration, tiles 0..13 --------------------
#pragma unroll 1
    for (int tt = 0; tt < 7; ++tt) {
        const int t0 = 2 * tt;
        TILE(t0,     0, 1, 1, VM4);
        TILE(t0 + 1, 1, 1, 1, VM4);
    }
    // tail: t=14 stages A(15) only, drains; t=15 stages nothing
    TILE(14, 0, 1, 0, VM0);
    TILE(15, 1, 0, 0, {});

    // ---- fused epilogue (round-8 math, 8 frags / 4 chunks) ----------------
    float bv[4];
#pragma unroll
    for (int j = 0; j < 4; ++j)
        bv[j] = biasp[n0 + wc * 64 + j * 16 + lane15];

    const int chbase = ((n0 + wc * 64) >> 1) + lane15;   // + jp*16

    float Ai[8][2], Bi[8][2];   // per-(i-frag, jp) 16-row affine summaries

#pragma unroll
    for (int i = 0; i < 8; ++i) {
        float A[2] = {1.f, 1.f};
        float Bc[2] = {0.f, 0.f};
#pragma unroll
        for (int r = 0; r < 4; ++r) {
            const size_t row = (size_t)(m0 + wr * 128 + i * 16 + quad * 4 + r);
            __half2* prow = avbuf + row * H_DIM + chbase;
#pragma unroll
            for (int jp = 0; jp < 2; ++jp) {
                const float z  = acc[i][2 * jp][r]     + bv[2 * jp];
                const float hh = acc[i][2 * jp + 1][r] + bv[2 * jp + 1];
                float a, v;
                gate_av(z, hh, a, v);
                const __half2 h2 = __floats2half2_rn(a, v);
                prow[jp * 16] = h2;
                // compose with the SAME fp16-rounded values phase3 will use
                const float2 f = __half22float2(h2);
                Bc[jp] = fmaf(f.x, Bc[jp], f.y);
                A[jp] *= f.x;
            }
        }
        // ordered compose across quads (rows i*16 + quad*4 + r are
        // (quad,r)-lexicographic): butterfly on lane bits 16 and 32.
#pragma unroll
        for (int jp = 0; jp < 2; ++jp) {
#pragma unroll
            for (int d = 16; d < 64; d <<= 1) {
                const float Ay = __shfl_xor(A[jp],  d);
                const float By = __shfl_xor(Bc[jp], d);
                // bit set -> I am the LATER block: (A,B) o (Ay,By)
                Bc[jp] = (lane & d) ? fmaf(A[jp], By, Bc[jp])
                                    : fmaf(Ay, Bc[jp], By);
                A[jp] *= Ay;
            }
            Ai[i][jp] = A[jp];
            Bi[i][jp] = Bc[jp];
        }
    }

    // chunk (32 rows) = frags {2cc, 2cc+1}; all quads hold identical values,
    // quad 0 writes.
    if (lane < 16) {
#pragma unroll
        for (int cc = 0; cc < 4; ++cc) {
            const int grow = m0 + wr * 128 + cc * 32;
            const int n    = grow >> 12;                  // batch
            const int cch  = (grow & (L_SEQ - 1)) >> 5;   // chunk id
            const size_t o = (size_t)cch * NCH + (size_t)n * H_DIM + chbase;
#pragma unroll
            for (int jp = 0; jp < 2; ++jp) {
                const float A0 = Ai[2 * cc][jp],     B0 = Bi[2 * cc][jp];
                const float A1 = Ai[2 * cc + 1][jp], B1 = Bi[2 * cc + 1][jp];
                Aar[o + jp * 16] = A1 * A0;
                Bar[o + jp * 16] = fmaf(A1, B0, B1);
            }
        }
    }
}

// ---------------------------------------------------------------------------
// Phase 2: compose NCHUNK chunk summaries per channel, seeded with hx (fp32).
// ---------------------------------------------------------------------------
__global__ __launch_bounds__(256) void scan_phase2(
    const float* __restrict__ Aar, const float* __restrict__ Bar,
    const float* __restrict__ hx, float* __restrict__ seed)
{
    const int ch = blockIdx.x * 256 + threadIdx.x;    // 0..8191
    float carry = hx[ch];
#pragma unroll 8
    for (int c = 0; c < NCHUNK; ++c) {
        seed[c * NCH + ch] = carry;
        carry = fmaf(Aar[c * NCH + ch], carry, Bar[c * NCH + ch]);
    }
}

// ---------------------------------------------------------------------------
// Phase 3: pure replay from seed: h = fma(a, h, v).  4 ch/thread, 16B av
// loads, nontemporal fp32 stores.
// ---------------------------------------------------------------------------
__global__ __launch_bounds__(256) void scan_phase3(
    const __half2* __restrict__ avbuf,
    const float* __restrict__ seed, float* __restrict__ out)
{
    const int idx = blockIdx.x * 256 + threadIdx.x;
    const int h4  = (idx & 255) << 2;
    const int n   = (idx >> 8) & 7;
    const int c   = idx >> 11;
    const size_t base = ((size_t)(n * L_SEQ + c * CLEN)) * H_DIM + h4;
    const float4* avp = (const float4*)(avbuf + base);  // 4 half2 = 16B
    float* op = out + base;

    const size_t so = (size_t)c * NCH + n * H_DIM + h4;
    float h0[4];
    *(f32x4*)h0 = *(const f32x4*)(seed + so);

#pragma unroll 8
    for (int s = 0; s < CLEN; ++s) {
        float4 avr = avp[(size_t)s * (H_DIM / 4)];
        const __half2* a2 = (const __half2*)&avr;
#pragma unroll
        for (int j = 0; j < 4; ++j) {
            const float2 av = __half22float2(a2[j]);
            h0[j] = fmaf(av.x, h0[j], av.y);
        }
        f32x4 hv = *(const f32x4*)h0;
        __builtin_nontemporal_store(hv, (f32x4*)(op + (size_t)s * H_DIM));
    }
}

// ---------------------------------------------------------------------------
extern "C" void kernel_launch(void* const* d_in, const int* in_sizes, int n_in,
                              void* d_out, int out_size, void* d_ws, size_t ws_size,
                              hipStream_t stream)
{
    const float* X    = (const float*)d_in[0];   // x  (8,4096,1024) fp32
    const float* Wm   = (const float*)d_in[1];   // W  (2048,1024)   fp32
    const float* bias = (const float*)d_in[2];   // b  (2048)        fp32
    const float* hx   = (const float*)d_in[3];   // hx (8,1024)      fp32
    float* out = (float*)d_out;                  // (8,4096,1024)    fp32

    char* ws = (char*)d_ws;
    ushort_t* wb   = (ushort_t*)ws;                                 //   4 MiB
    __half2*  avbuf = (__half2*)(ws + (size_t)O_DIM * K_DIM * 2);   // 128 MiB
    float*    seed = (float*)((char*)avbuf + (size_t)M_TOT * H_DIM * 4); // 4 MiB
    float*    biasp = seed + (size_t)NCHUNK * NCH;                  //   8 KiB

    // d_out (128 MiB) doubles as scratch until phase3 overwrites it:
    //   bytes [0, 64Mi):   x_bf16  (M_TOT*K_DIM*2 B = exactly half)
    //   bytes [64Mi,72Mi): Aar, Bar (NCHUNK*NCH fp32 each)
    ushort_t* xb = (ushort_t*)d_out;
    float* Aar = out + (size_t)M_TOT * H_DIM / 2;      // true halfway point
    float* Bar = Aar + (size_t)NCHUNK * NCH;

    cvt_w_perm<<<O_DIM * K_DIM / 8 / 256, 256, 0, stream>>>(Wm, wb, bias, biasp);
    cvt_f32_bf16<<<M_TOT * K_DIM / 8 / 256, 256, 0, stream>>>(X, xb);

    dim3 ggrid(O_DIM / BN, M_TOT / BM);          // (8, 128)
    gemm_zh<<<ggrid, 512, 0, stream>>>(xb, wb, biasp, avbuf, Aar, Bar);

    scan_phase2<<<NCH / 256, 256, 0, stream>>>(Aar, Bar, hx, seed);

    const int p3_blocks = (NCH / 4) * NCHUNK / 256;    // 1024
    scan_phase3<<<p3_blocks, 256, 0, stream>>>(avbuf, seed, out);
}